// Round 1
// 116.818 us; speedup vs baseline: 1.1216x; 1.1216x over previous
//
#include <hip/hip_runtime.h>
#include <math.h>

#define N_BOX 8192
#define NW 128              // 8192 / 64 words per row
#define LCAP 24576          // edges staged in LDS (96 KiB)
#define ECAP_MAX (1 << 21)  // max edges in global buffer (8 MiB)
#define NCH 8               // candidate chunks for rank kernel
#define CH 1024             // N_BOX / NCH candidates per chunk
#define THR_C 0.7f
#define IOU_THR_C 0.5f
#define EPS_C 1e-9f

// SCALER = max(3508/1280, 2480/1280) computed in double then rounded to f32,
// matching numpy/jax float32 weak-typed scalar promotion.
__device__ __constant__ float kScaler = (float)(3508.0 / 1280.0);

static __device__ __forceinline__ unsigned long long make_key(const float* conf, int i) {
    float c0 = conf[2 * i], c1 = conf[2 * i + 1];
    bool valid = (c0 > THR_C) || (c1 > THR_C);
    float ms = valid ? fmaxf(c0, c1) : -INFINITY;
    unsigned int u = __float_as_uint(ms);
    unsigned int m = (u & 0x80000000u) ? ~u : (u | 0x80000000u); // ascending map
    unsigned int d = ~m;                                          // descending key
    return ((unsigned long long)d << 32) | (unsigned int)i;
}

// ---------------------------------------------------------------------------
// K1: build all 8192 sort keys (u64: descending-score | index, unique) and
// zero the global counters. Ascending u64 order == stable argsort(-score):
// valid keys sort strictly before all invalid (-inf) keys.
// ---------------------------------------------------------------------------
__global__ __launch_bounds__(256) void key_kernel(const float* __restrict__ conf,
                                                  unsigned long long* __restrict__ keys,
                                                  int* __restrict__ ecntE,
                                                  int* __restrict__ nvD) {
    int i = blockIdx.x * 256 + threadIdx.x;
    if (i == 0) { *ecntE = 0; *nvD = 0; }
    keys[i] = make_key(conf, i);
}

// ---------------------------------------------------------------------------
// K2: rank sort, partial counts. rank(i) = #{j : key_j < key_i} is an exact
// stable permutation (keys unique). Grid = 32 element-chunks x 8 candidate-
// chunks = 256 blocks (all CUs). Candidate keys are read with uniform index
// (loop counter) -> scalar/broadcast loads; no LDS, no barriers. ~2 VALU
// instr per candidate with 4 independent accumulators.
// ---------------------------------------------------------------------------
__global__ __launch_bounds__(256) void rank_kernel(const unsigned long long* __restrict__ keys,
                                                   int* __restrict__ partial) {
    int i = blockIdx.x * 256 + threadIdx.x;
    unsigned long long ki = keys[i];
    const ulonglong4* kp = (const ulonglong4*)(keys + blockIdx.y * CH);
    int c0 = 0, c1 = 0, c2 = 0, c3 = 0;
#pragma unroll 4
    for (int l = 0; l < CH / 4; ++l) {
        ulonglong4 kq = kp[l];
        c0 += (kq.x < ki) ? 1 : 0;
        c1 += (kq.y < ki) ? 1 : 0;
        c2 += (kq.z < ki) ? 1 : 0;
        c3 += (kq.w < ki) ? 1 : 0;
    }
    partial[blockIdx.y * N_BOX + i] = (c0 + c1) + (c2 + c3);
}

// ---------------------------------------------------------------------------
// K3: sum partial ranks, scatter boxes/order by rank, count valid (nv).
// Valid boxes land exactly in ranks [0, nv): for a valid i, every smaller key
// is also valid. Invalid boxes are NOT scattered — their output rows are
// forced to zero downstream, so sb/order at ranks >= nv are never consumed.
// ---------------------------------------------------------------------------
__global__ __launch_bounds__(256) void scatter_kernel(const float* __restrict__ conf,
                                                      const float* __restrict__ bboxes,
                                                      const int* __restrict__ partial,
                                                      float4* __restrict__ sb,
                                                      unsigned int* __restrict__ order,
                                                      int* __restrict__ nvD) {
    int i = blockIdx.x * 256 + threadIdx.x;
    int r = 0;
#pragma unroll
    for (int c = 0; c < NCH; ++c) r += partial[c * N_BOX + i];
    float c0 = conf[2 * i], c1 = conf[2 * i + 1];
    bool valid = (c0 > THR_C) || (c1 > THR_C);
    if (valid) {
        sb[r] = ((const float4*)bboxes)[i];
        order[r] = (unsigned int)i;
    }
    unsigned long long vb = __ballot(valid);
    if ((threadIdx.x & 63) == 0) atomicAdd(nvD, __popcll(vb));
}

// ---------------------------------------------------------------------------
// K4: pair kernel — COMPACT EDGE LIST only (no mask matrix).
// Valid boxes are exactly ranks [0,nv), so the IoU domain is the nv x nv
// upper triangle. Whole blocks outside it exit immediately. Edge =
// (src<<13)|tgt, both valid, iou > thr, tgt > src; exact IEEE fp32 arithmetic
// identical to the reference. Wave-aggregated append. Poisoned sb reads for
// j >= nv are masked out by tmask before use.
// ---------------------------------------------------------------------------
__global__ void pair_kernel(const float4* __restrict__ sb,
                            const int* __restrict__ nvD,
                            unsigned int* __restrict__ edges,
                            int* __restrict__ ecntE,
                            int ecap) {
    int w = blockIdx.y;
    int jbase = w << 6;
    int ibase = blockIdx.x * 256;
    int nv = *nvD;
    if (ibase >= nv || jbase >= nv || jbase + 63 <= ibase) return;  // uniform
    __shared__ float4 cb[64];
    __shared__ float carea[64];
    if (threadIdx.x < 64) {
        float4 c = sb[jbase + threadIdx.x];
        cb[threadIdx.x] = c;
        carea[threadIdx.x] = (c.z - c.x) * (c.w - c.y);
    }
    __syncthreads();
    int i = ibase + threadIdx.x;
    unsigned long long bits = 0ull;
    if (i < nv && jbase + 63 > i) {
        float4 r = sb[i];
        float ra = (r.z - r.x) * (r.w - r.y);
#pragma unroll 8
        for (int b = 0; b < 64; ++b) {
            float4 c = cb[b];
            float iw = fminf(r.z, c.z) - fmaxf(r.x, c.x);
            float ih = fminf(r.w, c.w) - fmaxf(r.y, c.y);
            iw = fmaxf(iw, 0.0f);
            ih = fmaxf(ih, 0.0f);
            float inter = iw * ih;
            float iou = inter / (ra + carea[b] - inter + EPS_C);
            if ((iou > IOU_THR_C) && ((jbase + b) > i)) bits |= (1ull << b);
        }
    }
    // drop targets >= nv (invalid: can never be kept; also masks poison IoUs)
    unsigned long long tmask = (jbase + 64 <= nv) ? ~0ull
                               : ((1ull << (nv - jbase)) - 1ull);
    unsigned long long ebits = bits & tmask;
    int lane = threadIdx.x & 63;
    int ec = __popcll(ebits);
    int pre = ec;
#pragma unroll
    for (int d = 1; d < 64; d <<= 1) {
        int vv = __shfl_up(pre, d, 64);
        if (lane >= d) pre += vv;
    }
    int tot = __shfl(pre, 63, 64);
    if (tot > 0) {
        int base = 0;
        if (lane == 63) base = atomicAdd(ecntE, tot);
        base = __shfl(base, 63, 64);
        int idx = base + pre - ec;
        unsigned long long tb = ebits;
        while (tb) {
            int b = __builtin_ctzll(tb); tb &= tb - 1;
            if (idx < ecap) edges[idx] = ((unsigned int)i << 13) | (unsigned int)(jbase + b);
            ++idx;
        }
    }
}

// ---------------------------------------------------------------------------
// K5: Jacobi-iterated greedy NMS over the edge list (512 threads).
// Greedy NMS is the unique fixpoint of k[i] = v[i] & ~OR_{j<i,e(j,i)} k[j];
// Jacobi sweeps are exact for nodes of dependency depth <= t-1, so k_new ==
// k_old certifies convergence to the greedy solution. The valid mask is
// derived from nv alone (valid == rank < nv). Overflow (cnt > ecap, never
// expected) falls back to an on-the-fly serial greedy over ranks [0, nv).
// ---------------------------------------------------------------------------
__global__ __launch_bounds__(512) void scan_kernel(const unsigned int* __restrict__ edges,
                                                   const int* __restrict__ ecntE,
                                                   const int* __restrict__ nvD,
                                                   const float4* __restrict__ sb,
                                                   unsigned long long* __restrict__ keepK,
                                                   int ecap) {
    __shared__ unsigned int eL[LCAP];             // 96 KiB
    __shared__ unsigned long long kL[NW], tL[NW], vL[NW];
    __shared__ int chg[3];
    int t = threadIdx.x;
    int cnt = *ecntE;
    int nv = *nvD;
    if (t < NW) {
        int lo = t << 6;
        unsigned long long v;
        if (nv >= lo + 64)      v = ~0ull;
        else if (nv <= lo)      v = 0ull;
        else                    v = (1ull << (nv - lo)) - 1ull;
        vL[t] = v; kL[t] = v;
    }
    if (t == 0) { chg[0] = 0; chg[1] = 0; chg[2] = 0; }
    if (cnt <= ecap) {
        int lim = cnt < LCAP ? cnt : LCAP;
        for (int e = t; e < lim; e += 512) eL[e] = edges[e];
    }
    __syncthreads();
    if (cnt <= ecap) {
        for (int it = 0; it < N_BOX; ++it) {
            if (t < NW) tL[t] = 0ull;
            __syncthreads();
            for (int e = t; e < cnt; e += 512) {
                unsigned int ed = (e < LCAP) ? eL[e] : edges[e];
                int src = (int)(ed >> 13);
                if ((kL[src >> 6] >> (src & 63)) & 1ull) {
                    int tg = (int)(ed & 8191u);
                    atomicOr(&tL[tg >> 6], 1ull << (tg & 63));
                }
            }
            __syncthreads();
            if (t < NW) {
                unsigned long long nk = vL[t] & ~tL[t];
                if (nk != kL[t]) chg[it % 3] = 1;
                kL[t] = nk;
            }
            if (t == 0) chg[(it + 2) % 3] = 0;   // reset 2 barriers before reuse
            __syncthreads();
            if (chg[it % 3] == 0) break;         // uniform: read after barrier
        }
    } else {
        // fallback: serial greedy over ranks [0,nv), IoU on the fly (one wave)
        if (t < NW) tL[t] = 0ull;
        __syncthreads();
        if (t < 64) {
            int lane = t;
            for (int i = 0; i < nv - 1; ++i) {
                bool rem = (tL[i >> 6] >> (i & 63)) & 1ull;
                if (!rem) {
                    float4 r = sb[i];
                    float ra = (r.z - r.x) * (r.w - r.y);
                    for (int j = i + 1 + lane; j < nv; j += 64) {
                        float4 c = sb[j];
                        float ca = (c.z - c.x) * (c.w - c.y);
                        float iw = fminf(r.z, c.z) - fmaxf(r.x, c.x);
                        float ih = fminf(r.w, c.w) - fmaxf(r.y, c.y);
                        iw = fmaxf(iw, 0.0f);
                        ih = fmaxf(ih, 0.0f);
                        float inter = iw * ih;
                        float iou = inter / (ra + ca - inter + EPS_C);
                        if (iou > IOU_THR_C) atomicOr(&tL[j >> 6], 1ull << (j & 63));
                    }
                }
            }
        }
        __syncthreads();
        if (t < NW) kL[t] = vL[t] & ~tL[t];
    }
    __syncthreads();
    if (t < NW) keepK[t] = kL[t];
}

// ---------------------------------------------------------------------------
// K6: write (N,6) output: kept rows = [boxes*SCALER, conf]; all other rows
// (suppressed valid + all invalid) are exactly 0.0 in the reference (positive
// boxes/conf * 0), so write literal zeros and never touch sb/order for them
// (ranks >= nv hold workspace poison).
// ---------------------------------------------------------------------------
__global__ void out_kernel(const float4* __restrict__ sb,
                           const unsigned long long* __restrict__ keepK,
                           const unsigned int* __restrict__ order,
                           const float* __restrict__ conf,
                           float* __restrict__ out) {
    int i = blockIdx.x * 256 + threadIdx.x;
    bool kept = (keepK[i >> 6] >> (i & 63)) & 1ull;
    if (kept) {
        float4 b = sb[i];
        unsigned int o = order[i];
        out[i * 6 + 0] = b.x * kScaler;
        out[i * 6 + 1] = b.y * kScaler;
        out[i * 6 + 2] = b.z * kScaler;
        out[i * 6 + 3] = b.w * kScaler;
        out[i * 6 + 4] = conf[2 * o];
        out[i * 6 + 5] = conf[2 * o + 1];
    } else {
        out[i * 6 + 0] = 0.0f;
        out[i * 6 + 1] = 0.0f;
        out[i * 6 + 2] = 0.0f;
        out[i * 6 + 3] = 0.0f;
        out[i * 6 + 4] = 0.0f;
        out[i * 6 + 5] = 0.0f;
    }
}

extern "C" void kernel_launch(void* const* d_in, const int* in_sizes, int n_in,
                              void* d_out, int out_size, void* d_ws, size_t ws_size,
                              hipStream_t stream) {
    const float* cls_conf = (const float*)d_in[0];   // (8192, 2)
    const float* bboxes   = (const float*)d_in[1];   // (8192, 4)
    float* out = (float*)d_out;                      // (8192, 6)

    char* ws = (char*)d_ws;
    unsigned long long* keys    = (unsigned long long*)(ws + 0);        //  64 KiB
    int*                partial = (int*)(ws + 65536);                   // 256 KiB
    float4*             sb      = (float4*)(ws + 327680);               // 128 KiB
    unsigned int*       order   = (unsigned int*)(ws + 458752);         //  32 KiB
    int*                ecntE   = (int*)(ws + 491520);                  //   4 B
    int*                nvD     = (int*)(ws + 491524);                  //   4 B
    unsigned long long* keepK   = (unsigned long long*)(ws + 492032);   //   1 KiB
    const size_t EDGE_OFF = 493568;
    unsigned int*       edges   = (unsigned int*)(ws + EDGE_OFF);
    size_t avail = (ws_size > EDGE_OFF + 16) ? (ws_size - EDGE_OFF) / 4 : 0;
    int ecap = (int)(avail > (size_t)ECAP_MAX ? (size_t)ECAP_MAX : avail);

    key_kernel<<<N_BOX / 256, 256, 0, stream>>>(cls_conf, keys, ecntE, nvD);
    rank_kernel<<<dim3(N_BOX / 256, NCH), 256, 0, stream>>>(keys, partial);
    scatter_kernel<<<N_BOX / 256, 256, 0, stream>>>(cls_conf, bboxes, partial, sb, order, nvD);
    pair_kernel<<<dim3(32, 128), 256, 0, stream>>>(sb, nvD, edges, ecntE, ecap);
    scan_kernel<<<1, 512, 0, stream>>>(edges, ecntE, nvD, sb, keepK, ecap);
    out_kernel<<<N_BOX / 256, 256, 0, stream>>>(sb, keepK, order, cls_conf, out);
}